// Round 11
// baseline (274.341 us; speedup 1.0000x reference)
//
#include <hip/hip_runtime.h>
#include <hip/hip_bf16.h>
#include <climits>

#define B_ 2
#define V_ 4
#define H_ 120
#define W_ 160
#define C_ 96
#define NVOX 200000
#define GRID_ 128
#define NSTEPS 156
#define NRAYS (B_*V_*H_*W_)       // 153600
#define NB1 ((NVOX + 255) / 256)  // 782 blocks over voxels
#define CHUNK 32                  // sorted-list entries per wave in chunk_reduce
#define NCHUNK ((NRAYS + CHUNK - 1) / CHUNK)  // 4800 max chunks
#define PARR 8                    // step-blocks per ray in march (8 px/wave)

// ---- Kernel A: per-batch min via atomicMax(127-coord) (sneg zero-init) -----
__global__ void shift_kernel(const int* __restrict__ coords, int* __restrict__ sneg) {
    __shared__ int smax[B_ * 3];
    int t = threadIdx.x;
    if (t < B_ * 3) smax[t] = 0;
    __syncthreads();
    int i = blockIdx.x * blockDim.x + t;
    if (i < NVOX) {
        int4 cc = ((const int4*)coords)[i];
        atomicMax(&smax[cc.x * 3 + 0], 127 - cc.y);
        atomicMax(&smax[cc.x * 3 + 1], 127 - cc.z);
        atomicMax(&smax[cc.x * 3 + 2], 127 - cc.w);
    }
    __syncthreads();
    if (t < B_ * 3 && smax[t] > 0) atomicMax(&sneg[t], smax[t]);
}

// ------- Kernel B: occ id grid (last-dup wins) + 64-bit occupancy bitmask ---
// occ is NOT pre-initialized (poison irrelevant: mask gates all reads).
__global__ void occ_kernel(const int* __restrict__ coords,
                           const int* __restrict__ sneg,
                           int* __restrict__ occ,
                           unsigned long long* __restrict__ mask) {
    int i = blockIdx.x * blockDim.x + threadIdx.x;
    if (i >= NVOX) return;
    int4 cc = ((const int4*)coords)[i];
    int b = cc.x;
    int x = cc.y - (127 - sneg[b * 3 + 0]);
    int y = cc.z - (127 - sneg[b * 3 + 1]);
    int z = cc.w - (127 - sneg[b * 3 + 2]);
    int idx = ((b * GRID_ + z) * GRID_ + y) * GRID_ + x;
    atomicMax(&occ[idx], i);
    atomicOr(&mask[idx >> 6], 1ull << (idx & 63));
}

// -------- Kernel C: march, 8 px/wave x 8 step-blocks (64-step windows) ------
// Wider windows shrink the divergent max-of-pixels wait: E[rounds] ~2.2 vs
// ~4.3 at 32-step windows. Probes stay coalesced (8 adjacent pixels/sub).
// cnt update is wave-aggregated over the 8 result lanes (runs up to 8).
__global__ void march_kernel(const float* __restrict__ vm,
                             const float* __restrict__ intr,
                             const int* __restrict__ sneg,
                             const unsigned long long* __restrict__ mask,
                             const int* __restrict__ occ,
                             int* __restrict__ tgt,
                             int* __restrict__ cnt) {
    int gt   = blockIdx.x * blockDim.x + threadIdx.x;
    int lane = threadIdx.x & 63;
    int p    = lane & 7;                 // pixel 0..7
    int sub  = lane >> 3;                // step-block 0..7 (8 steps each)
    int r    = ((gt >> 6) << 3) + p;     // 8 consecutive rays per wave
    if (r >= NRAYS) return;
    int w = r % W_;
    int h = (r / W_) % H_;
    int v = (r / (W_ * H_)) % V_;
    int b = r / (W_ * H_ * V_);
    const float* M = vm + (size_t)(b * V_ + v) * 16;
    float fx = intr[0], fy = intr[1], cx = intr[2], cy = intr[3];
    float dx = ((float)w + 0.5f - cx) / fx;
    float dy = ((float)h + 0.5f - cy) / fy;
    // d = R * (dx, dy, 1)
    float d0 = M[0] * dx + M[1] * dy + M[2];
    float d1 = M[4] * dx + M[5] * dy + M[6];
    float d2 = M[8] * dx + M[9] * dy + M[10];
    float t0 = M[3]  - (float)(127 - sneg[b * 3 + 0]);
    float t1 = M[7]  - (float)(127 - sneg[b * 3 + 1]);
    float t2 = M[11] - (float)(127 - sneg[b * 3 + 2]);
    const int vbase = b * GRID_ * GRID_ * GRID_;
    const int MISS = 0x7FFFFFFF;
    int beststep = MISS;
    for (int w0 = 0; w0 < NSTEPS; w0 += 64) {
        int lin[8]; bool ok[8];
#pragma unroll
        for (int j = 0; j < 8; ++j) {
            int st = w0 + sub * 8 + j;
            float t = 2.0f + 0.5f * (float)st;
            float pwx = d0 * t + t0;
            float pwy = d1 * t + t1;
            float pwz = d2 * t + t2;
            int ix = (int)floorf(pwx);
            int iy = (int)floorf(pwy);
            int iz = (int)floorf(pwz);
            ok[j] = ((unsigned)ix < (unsigned)GRID_) &
                    ((unsigned)iy < (unsigned)GRID_) &
                    ((unsigned)iz < (unsigned)GRID_) & (st < NSTEPS);
            int cix = min(max(ix, 0), GRID_ - 1);
            int ciy = min(max(iy, 0), GRID_ - 1);
            int ciz = min(max(iz, 0), GRID_ - 1);
            lin[j] = vbase + (ciz << 14) + (ciy << 7) + cix;
        }
        unsigned long long u[8];
        bool same[8];
        same[0] = false;
#pragma unroll
        for (int j = 1; j < 8; ++j) same[j] = ((lin[j] >> 6) == (lin[j - 1] >> 6));
#pragma unroll
        for (int j = 0; j < 8; ++j)
            if (!same[j]) u[j] = mask[lin[j] >> 6];
#pragma unroll
        for (int j = 1; j < 8; ++j)
            if (same[j]) u[j] = u[j - 1];
        int local = MISS;
#pragma unroll
        for (int j = 0; j < 8; ++j) {
            int st = w0 + sub * 8 + j;
            if (ok[j] && ((u[j] >> (lin[j] & 63)) & 1ull)) local = min(local, st);
        }
        // reduce over the 8 step-blocks of this pixel (stride-8 lanes)
        local = min(local, __shfl_xor(local, 8));
        local = min(local, __shfl_xor(local, 16));
        local = min(local, __shfl_xor(local, 32));
        if (local != MISS) { beststep = local; break; }
    }
    // resolve first-hit id (only the 8 result lanes read occ)
    int res = -1;
    if (sub == 0) {
        if (beststep != MISS) {
            float t = 2.0f + 0.5f * (float)beststep;
            int ix = (int)floorf(d0 * t + t0);
            int iy = (int)floorf(d1 * t + t1);
            int iz = (int)floorf(d2 * t + t2);
            res = occ[vbase + (iz << 14) + (iy << 7) + ix];
        }
        tgt[r] = res;
    }
    // wave-aggregated histogram: one atomic per contiguous equal-target run
    bool active = (sub == 0) && (res >= 0);
    int prevres = __shfl_up(res, 1);
    bool head = active && (p == 0 || prevres != res);
    bool boundary = head || !active;
    unsigned long long bb = __ballot(boundary);
    if (head) {
        unsigned long long above = bb & ~((2ull << lane) - 1);  // boundaries > lane
        int next = above ? (__ffsll((long long)above) - 1) : 64;
        atomicAdd(&cnt[res], next - lane);                      // run length
    }
}

// ---- Kernel D: segment allocator + crossing worklist -----------------------
__global__ void alloc_kernel(const int* __restrict__ cnt,
                             int* __restrict__ gtotal,
                             int* __restrict__ segstart,
                             int* __restrict__ cursor,
                             int* __restrict__ wl,
                             int* __restrict__ wlcount) {
    __shared__ int wtot[4];
    int tid  = threadIdx.x;
    int lane = tid & 63;
    int wid  = tid >> 6;
    int i = blockIdx.x * 256 + tid;
    int c = (i < NVOX) ? cnt[i] : 0;
    int x = c;
#pragma unroll
    for (int d = 1; d < 64; d <<= 1) {
        int y = __shfl_up(x, d);
        if (lane >= d) x += y;
    }
    if (lane == 63) wtot[wid] = x;
    __syncthreads();
    if (tid == 0) {
        int s0 = wtot[0], s1 = wtot[1], s2 = wtot[2], s3 = wtot[3];
        int base = atomicAdd(gtotal, s0 + s1 + s2 + s3);
        wtot[0] = base;
        wtot[1] = base + s0;
        wtot[2] = base + s0 + s1;
        wtot[3] = base + s0 + s1 + s2;
    }
    __syncthreads();
    if (i >= NVOX) return;
    int s = wtot[wid] + (x - c);
    segstart[i] = s;
    cursor[i]   = s;
    if (c > 0 && (s / CHUNK) != ((s + c - 1) / CHUNK)) {
        int pidx = atomicAdd(wlcount, 1);
        wl[pidx] = i;                 // crossing voxel -> finalize worklist
    }
}

// ---- Kernel E: wave-aggregated bucket scatter ------------------------------
__global__ void order_kernel(const int* __restrict__ tgt,
                             int* __restrict__ cursor, int2* __restrict__ sorted_rt) {
    int r = blockIdx.x * blockDim.x + threadIdx.x;   // grid is exactly NRAYS
    int lane = threadIdx.x & 63;
    int t = tgt[r];
    bool active = t >= 0;
    int prev = __shfl_up(t, 1);
    bool head = active && (lane == 0 || prev != t);
    bool boundary = head || !active;
    unsigned long long bb = __ballot(boundary);
    unsigned long long below = bb & ((2ull << lane) - 1);   // bits 0..lane
    int headpos = 63 - __clzll(below | 1ull);               // nearest boundary <= lane
    int base = 0;
    if (head) {
        unsigned long long above = bb & ~((2ull << lane) - 1);  // bits > lane
        int next = above ? (__ffsll((long long)above) - 1) : 64;
        int runlen = next - lane;
        base = atomicAdd(&cursor[t], runlen);
    }
    base = __shfl(base, headpos);
    if (active) sorted_rt[base + (lane - headpos)] = make_int2(r, t);
}

// ---------------- run flush: middle runs need no cnt/segstart ---------------
__device__ __forceinline__ void flush_run2(int t, int ks, int ke, int n,
                                           float ax, float ay, int lane,
                                           const int* __restrict__ segstart,
                                           const int* __restrict__ cnt,
                                           float* __restrict__ out,
                                           float* __restrict__ cnt_out) {
    int c;
    bool complete;
    if (ks > 0 && ke < n) {          // middle run: whole segment inside chunk
        c = ke - ks;
        complete = true;
    } else {
        c = cnt[t];
        int s = segstart[t];
        complete = (s / CHUNK) == ((s + c - 1) / CHUNK);
    }
    if (complete) {
        float denom = (float)c + 0.0001f;
        if (lane < 48) {
            float2 wv; wv.x = ax / denom; wv.y = ay / denom;
            ((float2*)(out + (size_t)t * C_))[lane] = wv;
        }
        if (lane == 0) cnt_out[t] = (float)c;
    } else if (lane < 48) {          // crossing: accumulate into memset-zeroed row
        unsafeAtomicAdd(out + (size_t)t * C_ + 2 * lane,     ax);
        unsafeAtomicAdd(out + (size_t)t * C_ + 2 * lane + 1, ay);
    }
}

// ---------------- Kernel F: chunked segmented reduce (16-deep pipeline) -----
__global__ void chunk_reduce_kernel(const float* __restrict__ feats,
                                    const int2* __restrict__ sorted_rt,
                                    const int* __restrict__ segstart,
                                    const int* __restrict__ cnt,
                                    const int* __restrict__ total_p,
                                    float* __restrict__ out,
                                    float* __restrict__ cnt_out) {
    int wave = (blockIdx.x * blockDim.x + threadIdx.x) >> 6;
    int lane = threadIdx.x & 63;
    int total = total_p[0];
    int a = wave * CHUNK;
    if (a >= total) return;
    int n = min(CHUNK, total - a);
    int myr = 0, myt = 0;
    if (lane < n) { int2 e = sorted_rt[a + lane]; myr = e.x; myt = e.y; }
    float ax = 0.0f, ay = 0.0f;
    int cur = -1, run_start = 0;
    for (int k0 = 0; k0 < n; k0 += 16) {
        float2 vbuf[16]; int tt[16];
#pragma unroll
        for (int j = 0; j < 16; ++j) {            // issue 16 feature loads
            int k = k0 + j;
            int rr = __shfl(myr, k);
            tt[j]  = __shfl(myt, k);
            vbuf[j] = make_float2(0.0f, 0.0f);
            if (k < n && lane < 48)
                vbuf[j] = ((const float2*)(feats + (size_t)rr * C_))[lane];
        }
#pragma unroll
        for (int j = 0; j < 16; ++j) {
            int k = k0 + j;
            if (k >= n) break;
            if (tt[j] != cur) {
                if (cur >= 0)
                    flush_run2(cur, run_start, k, n, ax, ay, lane, segstart, cnt, out, cnt_out);
                cur = tt[j]; run_start = k; ax = 0.0f; ay = 0.0f;
            }
            ax += vbuf[j].x; ay += vbuf[j].y;
        }
    }
    flush_run2(cur, run_start, n, n, ax, ay, lane, segstart, cnt, out, cnt_out);
}

// ---- Kernel G: finalize crossing voxels from worklist ----------------------
// Empty rows + empty cnt_out covered by the d_out memset.
__global__ void finalize_kernel(const int* __restrict__ wl,
                                const int* __restrict__ wlcount,
                                const int* __restrict__ cnt,
                                float* __restrict__ out,
                                float* __restrict__ cnt_out) {
    int idx  = (blockIdx.x * blockDim.x + threadIdx.x) >> 6;
    int lane = threadIdx.x & 63;
    if (idx >= wlcount[0]) return;
    int vox = wl[idx];
    int c = cnt[vox];
    float denom = (float)c + 0.0001f;
    if (lane < 48) {
        float2* o = (float2*)(out + (size_t)vox * C_);
        float2 x = o[lane];
        x.x /= denom; x.y /= denom;
        o[lane] = x;
    }
    if (lane == 0) cnt_out[vox] = (float)c;
}

extern "C" void kernel_launch(void* const* d_in, const int* in_sizes, int n_in,
                              void* d_out, int out_size, void* d_ws, size_t ws_size,
                              hipStream_t stream) {
    const float* feats  = (const float*)d_in[0];
    const int*   coords = (const int*)d_in[1];
    const float* vm     = (const float*)d_in[2];
    const float* intr   = (const float*)d_in[3];

    float* out     = (float*)d_out;                  // NVOX*C_ floats
    float* cnt_out = out + (size_t)NVOX * C_;        // NVOX floats

    char* ws = (char*)d_ws;
    // --- zero region (one memset): sneg | cnt | mask | gtotal | wlcount ---
    int*                sneg    = (int*)(ws + 0);            // 24 B (pad to 64)
    int*                cnt     = (int*)(ws + 64);           // 800,000 B
    unsigned long long* mask    = (unsigned long long*)(ws + 800064); // 524,288 B
    int*                gtotal  = (int*)(ws + 1324352);      // 4 B
    int*                wlcount = (int*)(ws + 1324356);      // 4 B -> zero ends 1324360
    // --- uninitialized scratch ---
    int*  tgt       = (int*)(ws + 1324416);                  // 614,400 B
    int*  segstart  = (int*)(ws + 1938816);                  // 800,000 B
    int*  cursor    = (int*)(ws + 2738816);                  // 800,000 B
    int*  wl        = (int*)(ws + 3538816);                  // 19,200 B
    int2* sorted_rt = (int2*)(ws + 3558016);                 // 1,228,800 B
    int*  occ       = (int*)(ws + 4786816);                  // 33,554,432 B (mask-gated)

    hipMemsetAsync(ws, 0, 1324360, stream);                  // small zero region
    hipMemsetAsync(d_out, 0, (size_t)out_size * sizeof(float), stream); // 77 MB linear

    shift_kernel<<<NB1, 256, 0, stream>>>(coords, sneg);
    occ_kernel<<<NB1, 256, 0, stream>>>(coords, sneg, occ, mask);
    march_kernel<<<(NRAYS * PARR + 255) / 256, 256, 0, stream>>>(vm, intr, sneg, mask, occ, tgt, cnt);
    alloc_kernel<<<NB1, 256, 0, stream>>>(cnt, gtotal, segstart, cursor, wl, wlcount);
    order_kernel<<<NRAYS / 256, 256, 0, stream>>>(tgt, cursor, sorted_rt);
    chunk_reduce_kernel<<<(NCHUNK * 64 + 255) / 256, 256, 0, stream>>>(
        feats, sorted_rt, segstart, cnt, gtotal, out, cnt_out);
    finalize_kernel<<<(NCHUNK * 64 + 255) / 256, 256, 0, stream>>>(
        wl, wlcount, cnt, out, cnt_out);
}

// Round 12
// 249.968 us; speedup vs baseline: 1.0975x; 1.0975x over previous
//
#include <hip/hip_runtime.h>
#include <hip/hip_bf16.h>
#include <climits>

#define B_ 2
#define V_ 4
#define H_ 120
#define W_ 160
#define C_ 96
#define NVOX 200000
#define GRID_ 128
#define NSTEPS 156
#define NRAYS (B_*V_*H_*W_)       // 153600
#define NB1 ((NVOX + 255) / 256)  // 782 blocks over voxels
#define CHUNK 32                  // sorted-list entries per wave in chunk_reduce
#define NCHUNK ((NRAYS + CHUNK - 1) / CHUNK)  // 4800 max chunks
#define PARR 4                    // lanes cooperating per ray in march (16 px/wave)

// ---- Kernel A: per-batch min via atomicMax(127-coord) (sneg zero-init) -----
__global__ void shift_kernel(const int* __restrict__ coords, int* __restrict__ sneg) {
    __shared__ int smax[B_ * 3];
    int t = threadIdx.x;
    if (t < B_ * 3) smax[t] = 0;
    __syncthreads();
    int i = blockIdx.x * blockDim.x + t;
    if (i < NVOX) {
        int4 cc = ((const int4*)coords)[i];
        atomicMax(&smax[cc.x * 3 + 0], 127 - cc.y);
        atomicMax(&smax[cc.x * 3 + 1], 127 - cc.z);
        atomicMax(&smax[cc.x * 3 + 2], 127 - cc.w);
    }
    __syncthreads();
    if (t < B_ * 3 && smax[t] > 0) atomicMax(&sneg[t], smax[t]);
}

// ------- Kernel B: occ id grid (last-dup wins) + 64-bit occupancy bitmask ---
// occ is NOT pre-initialized (poison irrelevant: mask gates all reads).
__global__ void occ_kernel(const int* __restrict__ coords,
                           const int* __restrict__ sneg,
                           int* __restrict__ occ,
                           unsigned long long* __restrict__ mask) {
    int i = blockIdx.x * blockDim.x + threadIdx.x;
    if (i >= NVOX) return;
    int4 cc = ((const int4*)coords)[i];
    int b = cc.x;
    int x = cc.y - (127 - sneg[b * 3 + 0]);
    int y = cc.z - (127 - sneg[b * 3 + 1]);
    int z = cc.w - (127 - sneg[b * 3 + 2]);
    int idx = ((b * GRID_ + z) * GRID_ + y) * GRID_ + x;
    atomicMax(&occ[idx], i);
    atomicOr(&mask[idx >> 6], 1ull << (idx & 63));
}

// -------- Kernel C: march, 16 px/wave x 4 step-blocks (R10 form) ------------
__global__ void march_kernel(const float* __restrict__ vm,
                             const float* __restrict__ intr,
                             const int* __restrict__ sneg,
                             const unsigned long long* __restrict__ mask,
                             const int* __restrict__ occ,
                             int* __restrict__ tgt,
                             int* __restrict__ cnt) {
    int gt   = blockIdx.x * blockDim.x + threadIdx.x;
    int lane = threadIdx.x & 63;
    int p    = lane & 15;
    int sub  = lane >> 4;
    int r    = ((gt >> 6) << 4) + p;
    if (r >= NRAYS) return;
    int w = r % W_;
    int h = (r / W_) % H_;
    int v = (r / (W_ * H_)) % V_;
    int b = r / (W_ * H_ * V_);
    const float* M = vm + (size_t)(b * V_ + v) * 16;
    float fx = intr[0], fy = intr[1], cx = intr[2], cy = intr[3];
    float dx = ((float)w + 0.5f - cx) / fx;
    float dy = ((float)h + 0.5f - cy) / fy;
    float d0 = M[0] * dx + M[1] * dy + M[2];
    float d1 = M[4] * dx + M[5] * dy + M[6];
    float d2 = M[8] * dx + M[9] * dy + M[10];
    float t0 = M[3]  - (float)(127 - sneg[b * 3 + 0]);
    float t1 = M[7]  - (float)(127 - sneg[b * 3 + 1]);
    float t2 = M[11] - (float)(127 - sneg[b * 3 + 2]);
    const int vbase = b * GRID_ * GRID_ * GRID_;
    const int MISS = 0x7FFFFFFF;
    int beststep = MISS;
    for (int w0 = 0; w0 < NSTEPS; w0 += 32) {
        int lin[8]; bool ok[8];
#pragma unroll
        for (int j = 0; j < 8; ++j) {
            int st = w0 + sub * 8 + j;
            float t = 2.0f + 0.5f * (float)st;
            float pwx = d0 * t + t0;
            float pwy = d1 * t + t1;
            float pwz = d2 * t + t2;
            int ix = (int)floorf(pwx);
            int iy = (int)floorf(pwy);
            int iz = (int)floorf(pwz);
            ok[j] = ((unsigned)ix < (unsigned)GRID_) &
                    ((unsigned)iy < (unsigned)GRID_) &
                    ((unsigned)iz < (unsigned)GRID_) & (st < NSTEPS);
            int cix = min(max(ix, 0), GRID_ - 1);
            int ciy = min(max(iy, 0), GRID_ - 1);
            int ciz = min(max(iz, 0), GRID_ - 1);
            lin[j] = vbase + (ciz << 14) + (ciy << 7) + cix;
        }
        unsigned long long u[8];
        bool same[8];
        same[0] = false;
#pragma unroll
        for (int j = 1; j < 8; ++j) same[j] = ((lin[j] >> 6) == (lin[j - 1] >> 6));
#pragma unroll
        for (int j = 0; j < 8; ++j)
            if (!same[j]) u[j] = mask[lin[j] >> 6];
#pragma unroll
        for (int j = 1; j < 8; ++j)
            if (same[j]) u[j] = u[j - 1];
        int local = MISS;
#pragma unroll
        for (int j = 0; j < 8; ++j) {
            int st = w0 + sub * 8 + j;
            if (ok[j] && ((u[j] >> (lin[j] & 63)) & 1ull)) local = min(local, st);
        }
        local = min(local, __shfl_xor(local, 16));
        local = min(local, __shfl_xor(local, 32));
        if (local != MISS) { beststep = local; break; }
    }
    int res = -1;
    if (sub == 0) {
        if (beststep != MISS) {
            float t = 2.0f + 0.5f * (float)beststep;
            int ix = (int)floorf(d0 * t + t0);
            int iy = (int)floorf(d1 * t + t1);
            int iz = (int)floorf(d2 * t + t2);
            res = occ[vbase + (iz << 14) + (iy << 7) + ix];
        }
        tgt[r] = res;
    }
    // wave-aggregated histogram: one atomic per contiguous equal-target run
    bool active = (sub == 0) && (res >= 0);
    int prevres = __shfl_up(res, 1);
    bool head = active && (p == 0 || prevres != res);
    bool boundary = head || !active;
    unsigned long long bb = __ballot(boundary);
    if (head) {
        unsigned long long above = bb & ~((2ull << lane) - 1);
        int next = above ? (__ffsll((long long)above) - 1) : 64;
        atomicAdd(&cnt[res], next - lane);
    }
}

// ---- Kernel D: segment allocator + crossing worklist -----------------------
__global__ void alloc_kernel(const int* __restrict__ cnt,
                             int* __restrict__ gtotal,
                             int* __restrict__ segstart,
                             int* __restrict__ cursor,
                             int* __restrict__ wl,
                             int* __restrict__ wlcount) {
    __shared__ int wtot[4];
    int tid  = threadIdx.x;
    int lane = tid & 63;
    int wid  = tid >> 6;
    int i = blockIdx.x * 256 + tid;
    int c = (i < NVOX) ? cnt[i] : 0;
    int x = c;
#pragma unroll
    for (int d = 1; d < 64; d <<= 1) {
        int y = __shfl_up(x, d);
        if (lane >= d) x += y;
    }
    if (lane == 63) wtot[wid] = x;
    __syncthreads();
    if (tid == 0) {
        int s0 = wtot[0], s1 = wtot[1], s2 = wtot[2], s3 = wtot[3];
        int base = atomicAdd(gtotal, s0 + s1 + s2 + s3);
        wtot[0] = base;
        wtot[1] = base + s0;
        wtot[2] = base + s0 + s1;
        wtot[3] = base + s0 + s1 + s2;
    }
    __syncthreads();
    if (i >= NVOX) return;
    int s = wtot[wid] + (x - c);
    segstart[i] = s;
    cursor[i]   = s;
    if (c > 0 && (s / CHUNK) != ((s + c - 1) / CHUNK)) {
        int pidx = atomicAdd(wlcount, 1);
        wl[pidx] = i;                 // crossing voxel -> finalize worklist
    }
}

// ---- Kernel E: wave-aggregated bucket scatter ------------------------------
__global__ void order_kernel(const int* __restrict__ tgt,
                             int* __restrict__ cursor, int2* __restrict__ sorted_rt) {
    int r = blockIdx.x * blockDim.x + threadIdx.x;   // grid is exactly NRAYS
    int lane = threadIdx.x & 63;
    int t = tgt[r];
    bool active = t >= 0;
    int prev = __shfl_up(t, 1);
    bool head = active && (lane == 0 || prev != t);
    bool boundary = head || !active;
    unsigned long long bb = __ballot(boundary);
    unsigned long long below = bb & ((2ull << lane) - 1);
    int headpos = 63 - __clzll(below | 1ull);
    int base = 0;
    if (head) {
        unsigned long long above = bb & ~((2ull << lane) - 1);
        int next = above ? (__ffsll((long long)above) - 1) : 64;
        int runlen = next - lane;
        base = atomicAdd(&cursor[t], runlen);
    }
    base = __shfl(base, headpos);
    if (active) sorted_rt[base + (lane - headpos)] = make_int2(r, t);
}

// ---- run flush: completeness decided LOCALLY via neighbor targets ----------
// complete <=> run doesn't extend past either chunk edge. Incomplete boundary
// runs write a non-atomic partial to a private per-chunk slot:
//   slot0 = run starting at chunk begin, slot1 = run ending at chunk end.
__device__ __forceinline__ void flush_run3(int t, int ks, int ke, int n,
                                           int pt, int nt, int chunk_id,
                                           float ax, float ay, int lane,
                                           float* __restrict__ part,
                                           float* __restrict__ out,
                                           float* __restrict__ cnt_out) {
    bool ext_back  = (ks == 0) && (pt == t);
    bool ext_fwd   = (ke == n) && (nt == t);
    if (!ext_back && !ext_fwd) {               // complete: run == whole segment
        int c = ke - ks;
        float denom = (float)c + 0.0001f;
        if (lane < 48) {
            float2 wv; wv.x = ax / denom; wv.y = ay / denom;
            ((float2*)(out + (size_t)t * C_))[lane] = wv;
        }
        if (lane == 0) cnt_out[t] = (float)c;
    } else {
        int slot = 2 * chunk_id + ((ks == 0) ? 0 : 1);
        if (lane < 48) {
            float2 wv; wv.x = ax; wv.y = ay;
            ((float2*)(part + (size_t)slot * C_))[lane] = wv;
        }
    }
}

// ---------------- Kernel F: chunked segmented reduce (8-deep, atomic-free) --
__global__ void chunk_reduce_kernel(const float* __restrict__ feats,
                                    const int2* __restrict__ sorted_rt,
                                    const int* __restrict__ total_p,
                                    float* __restrict__ part,
                                    float* __restrict__ out,
                                    float* __restrict__ cnt_out) {
    int wave = (blockIdx.x * blockDim.x + threadIdx.x) >> 6;
    int lane = threadIdx.x & 63;
    int total = total_p[0];
    int a = wave * CHUNK;
    if (a >= total) return;
    int n = min(CHUNK, total - a);
    int myr = 0, myt = -2;
    if (lane < n) { int2 e = sorted_rt[a + lane]; myr = e.x; myt = e.y; }
    else if (lane == 32) { if (a > 0)         myt = sorted_rt[a - 1].y; }
    else if (lane == 33) { if (a + n < total) myt = sorted_rt[a + n].y; }
    int pt = __shfl(myt, 32);                  // target just before chunk
    int nt = __shfl(myt, 33);                  // target just after chunk
    float ax = 0.0f, ay = 0.0f;
    int cur = -1, run_start = 0;
    for (int k0 = 0; k0 < n; k0 += 8) {
        float2 vbuf[8]; int tt[8];
#pragma unroll
        for (int j = 0; j < 8; ++j) {             // issue 8 feature loads
            int k = k0 + j;
            int rr = __shfl(myr, k);
            tt[j]  = __shfl(myt, k);
            vbuf[j] = make_float2(0.0f, 0.0f);
            if (k < n && lane < 48)
                vbuf[j] = ((const float2*)(feats + (size_t)rr * C_))[lane];
        }
#pragma unroll
        for (int j = 0; j < 8; ++j) {
            int k = k0 + j;
            if (k >= n) break;
            if (tt[j] != cur) {
                if (cur >= 0)
                    flush_run3(cur, run_start, k, n, pt, nt, wave,
                               ax, ay, lane, part, out, cnt_out);
                cur = tt[j]; run_start = k; ax = 0.0f; ay = 0.0f;
            }
            ax += vbuf[j].x; ay += vbuf[j].y;
        }
    }
    flush_run3(cur, run_start, n, n, pt, nt, wave, ax, ay, lane, part, out, cnt_out);
}

// ---- Kernel G: finalize crossing voxels: sum private partials, divide ------
// Voxel segment [s, s+c): first chunk contributes slot1 (or slot0 if aligned),
// subsequent chunks slot0. Every slot read is written by chunk_reduce.
__global__ void finalize_kernel(const int* __restrict__ wl,
                                const int* __restrict__ wlcount,
                                const int* __restrict__ cnt,
                                const int* __restrict__ segstart,
                                const float* __restrict__ part,
                                float* __restrict__ out,
                                float* __restrict__ cnt_out) {
    int idx  = (blockIdx.x * blockDim.x + threadIdx.x) >> 6;
    int lane = threadIdx.x & 63;
    if (idx >= wlcount[0]) return;
    int vox = wl[idx];
    int c = cnt[vox];
    int s = segstart[vox];
    int c0 = s / CHUNK, ce = (s + c - 1) / CHUNK;
    float ax = 0.0f, ay = 0.0f;
    if (lane < 48) {
        int slot0 = 2 * c0 + ((s % CHUNK) ? 1 : 0);
        float2 x = ((const float2*)(part + (size_t)slot0 * C_))[lane];
        ax = x.x; ay = x.y;
        for (int cc = c0 + 1; cc <= ce; ++cc) {
            float2 y = ((const float2*)(part + (size_t)(2 * cc) * C_))[lane];
            ax += y.x; ay += y.y;
        }
        float denom = (float)c + 0.0001f;
        float2 wv; wv.x = ax / denom; wv.y = ay / denom;
        ((float2*)(out + (size_t)vox * C_))[lane] = wv;
    }
    if (lane == 0) cnt_out[vox] = (float)c;
}

extern "C" void kernel_launch(void* const* d_in, const int* in_sizes, int n_in,
                              void* d_out, int out_size, void* d_ws, size_t ws_size,
                              hipStream_t stream) {
    const float* feats  = (const float*)d_in[0];
    const int*   coords = (const int*)d_in[1];
    const float* vm     = (const float*)d_in[2];
    const float* intr   = (const float*)d_in[3];

    float* out     = (float*)d_out;                  // NVOX*C_ floats
    float* cnt_out = out + (size_t)NVOX * C_;        // NVOX floats

    char* ws = (char*)d_ws;
    // --- zero region (one memset): sneg | cnt | mask | gtotal | wlcount ---
    int*                sneg    = (int*)(ws + 0);            // 24 B (pad to 64)
    int*                cnt     = (int*)(ws + 64);           // 800,000 B
    unsigned long long* mask    = (unsigned long long*)(ws + 800064); // 524,288 B
    int*                gtotal  = (int*)(ws + 1324352);      // 4 B
    int*                wlcount = (int*)(ws + 1324356);      // 4 B -> zero ends 1324360
    // --- uninitialized scratch ---
    int*   tgt       = (int*)(ws + 1324416);                 // 614,400 B
    int*   segstart  = (int*)(ws + 1938816);                 // 800,000 B
    int*   cursor    = (int*)(ws + 2738816);                 // 800,000 B
    int*   wl        = (int*)(ws + 3538816);                 // 19,200 B
    int2*  sorted_rt = (int2*)(ws + 3558016);                // 1,228,800 B
    float* part      = (float*)(ws + 4786816);               // 3,686,400 B (2 slots/chunk)
    int*   occ       = (int*)(ws + 8473216);                 // 33,554,432 B (mask-gated)

    hipMemsetAsync(ws, 0, 1324360, stream);                  // small zero region
    hipMemsetAsync(d_out, 0, (size_t)out_size * sizeof(float), stream); // 77 MB linear

    shift_kernel<<<NB1, 256, 0, stream>>>(coords, sneg);
    occ_kernel<<<NB1, 256, 0, stream>>>(coords, sneg, occ, mask);
    march_kernel<<<(NRAYS * PARR + 255) / 256, 256, 0, stream>>>(vm, intr, sneg, mask, occ, tgt, cnt);
    alloc_kernel<<<NB1, 256, 0, stream>>>(cnt, gtotal, segstart, cursor, wl, wlcount);
    order_kernel<<<NRAYS / 256, 256, 0, stream>>>(tgt, cursor, sorted_rt);
    chunk_reduce_kernel<<<(NCHUNK * 64 + 255) / 256, 256, 0, stream>>>(
        feats, sorted_rt, gtotal, part, out, cnt_out);
    finalize_kernel<<<(NCHUNK * 64 + 255) / 256, 256, 0, stream>>>(
        wl, wlcount, cnt, segstart, part, out, cnt_out);
}